// Round 6
// baseline (511.962 us; speedup 1.0000x reference)
//
#include <hip/hip_runtime.h>
#include <hip/hip_bf16.h>

// FeatureInspector: ska (dynamic 3x3 per-group aggregation) -> *roi ->
// grouped conv3x3(G=8)+BN+ReLU -> conv1x1+BN -> out = ska + y
//
// R8 == R7 resubmit (R5 bench was an infra failure: container died twice;
//     source re-audited, no OOB/hang found).
// R7: ska barrier-drain fix (R6 evidence: VALUBusy 13.5% => ~2080 cy/wave
//     = 2 global-latency barrier drains + compute).
//  ska: 1 row/thread-block-row; dw/roi/x ALL per-thread batched loads
//       (dw is 8-lane-broadcast -> 1 line/instr; XCD swizzle keeps halo+dw
//       L2-local, proven FETCH=86MB in R5/R6). launch_bounds(256,4) for a
//       128-VGPR budget so the 13-load batch stays in flight. No coop
//       stage -> no global-coupled barrier. Single cheap LDS barrier for
//       the y0b transpose (VALU-fed writes only).
//       Tile stride 36->34 (4-way bank conflict -> 2-way free).
//       prepack folded into ska launch tail (one fewer dispatch).
//  conv1: implicit GEMM, 9 shifted K=32 MFMAs; LDS x-tile [px 18x18][ci32
//         pad40] bf16; batched staging; LDS-transposed epilogue.
//  conv2: register GEMM M=64px, N=256, K=256; A-slabs via global_load_lds
//         3-buffer pipeline, counted vmcnt.
//
// ws layout (bytes):
//   [0, 67108864)          y0b bf16 ska*roi, channel-last [b][g][hw][ci32]
//   [67108864, +67108864)  h1t bf16 [b][g][hw][ci32]
//   [134217728, +147456)   w1b bf16 [g][khw][co][ci32]
//   [134365184, +131072)   w2b bf16 [co][ci256]

#define HW 16384
#define EPS 1e-5f

typedef __bf16 bf16x8 __attribute__((ext_vector_type(8)));
typedef short short8 __attribute__((ext_vector_type(8)));
typedef short short4v __attribute__((ext_vector_type(4)));
typedef float floatx4 __attribute__((ext_vector_type(4)));

__device__ __forceinline__ unsigned short f2bf(float f) {
  unsigned u = __builtin_bit_cast(unsigned, f);
  unsigned r = u + 0x7FFFu + ((u >> 16) & 1u);
  return (unsigned short)(r >> 16);
}

__device__ __forceinline__ floatx4 mfma16(short8 a, short8 b, floatx4 c) {
  return __builtin_amdgcn_mfma_f32_16x16x32_bf16(
      __builtin_bit_cast(bf16x8, a), __builtin_bit_cast(bf16x8, b), c, 0, 0, 0);
}

// Block = one (b,g,h,wt): 32 ci x 32 w. Thread: ci=tid>>3, wq=tid&7, 4 w.
// All loads per-thread & batched; one cheap LDS barrier for y0b transpose.
// Grid XCD-chunked: XCD k owns batch k. Tail blocks (>=32768) do prepack.
__global__ __launch_bounds__(256, 4) void ska_kernel(
    const float* __restrict__ x, const float* __restrict__ dw,
    const float* __restrict__ roi, float* __restrict__ out,
    unsigned short* __restrict__ y0b,
    const float* __restrict__ w1, const float* __restrict__ w2,
    unsigned short* __restrict__ w1b, unsigned short* __restrict__ w2b) {
  __shared__ unsigned short tile[32 * 34];     // [w32][ci stride34]

  int phys = blockIdx.x;                       // 33312 = 32768 ska + 544 pp
  int tid  = threadIdx.x;

  if (phys >= 32768) {                         // folded prepack tail
    int o = (phys - 32768) * 256 + tid;        // 139264 = 73728 + 65536
    if (o < 73728) {
      int ci  = o & 31;
      int co  = (o >> 5) & 31;
      int khw = (o >> 10) % 9;
      int g   = (o >> 10) / 9;
      w1b[o] = f2bf(w1[((g * 32 + co) * 32 + ci) * 9 + khw]);
    } else {
      int p = o - 73728;
      w2b[p] = f2bf(w2[p]);
    }
    return;
  }

  int blk = (phys & 7) * 4096 + (phys >> 3);   // bijective (32768 % 8 == 0)
  int wt = blk & 3;
  int h  = (blk >> 2) & 127;
  int g  = (blk >> 9) & 7;
  int b  = blk >> 12;
  int ci = tid >> 3;
  int wq = tid & 7;
  int w0 = wt * 32 + wq * 4;
  int c  = g * 32 + ci;

  // batched loads: 9 dw (8-lane broadcast) + 1 roi + x window (3 rows)
  const float* dwb = dw + ((size_t)(b * 8 + g) * 9) * HW + h * 128 + w0;
  floatx4 wv[9];
#pragma unroll
  for (int k = 0; k < 9; ++k) wv[k] = *(const floatx4*)&dwb[k * HW];

  floatx4 rv = *(const floatx4*)&roi[(size_t)b * HW + h * 128 + w0];

  size_t base = ((size_t)(b * 256 + c)) * HW + h * 128 + w0;
  float xr[3][6];
#pragma unroll
  for (int kh = 0; kh < 3; ++kh) {
    int hh = h + kh - 1;
    if ((unsigned)hh < 128u) {                 // wave-uniform branch
      const float* xp = &x[base + (kh - 1) * 128];
      floatx4 m = *(const floatx4*)xp;
      xr[kh][0] = (w0 > 0) ? xp[-1] : 0.f;
      xr[kh][1] = m[0];
      xr[kh][2] = m[1];
      xr[kh][3] = m[2];
      xr[kh][4] = m[3];
      xr[kh][5] = (w0 < 124) ? xp[4] : 0.f;
    } else {
#pragma unroll
      for (int i = 0; i < 6; ++i) xr[kh][i] = 0.f;
    }
  }

  float s[4] = {0.f, 0.f, 0.f, 0.f};
#pragma unroll
  for (int kh = 0; kh < 3; ++kh)
#pragma unroll
    for (int kw = 0; kw < 3; ++kw) {
      floatx4 wk = wv[kh * 3 + kw];
#pragma unroll
      for (int j = 0; j < 4; ++j) s[j] += xr[kh][kw + j] * wk[j];
    }

  *(floatx4*)&out[base] = (floatx4){s[0], s[1], s[2], s[3]};

#pragma unroll
  for (int j = 0; j < 4; ++j)
    tile[(wq * 4 + j) * 34 + ci] = f2bf(s[j] * rv[j]);

  __syncthreads();                             // LDS-only dependency: cheap

  // cooperative coalesced y0b store: 2KB contiguous
  unsigned short* dst =
      y0b + ((size_t)(b * 8 + g) * HW + h * 128 + wt * 32) * 32;
  int w = tid >> 3, k = tid & 7;
  *(short4v*)&dst[tid * 4] = *(const short4v*)&tile[w * 34 + k * 4];
}

// Grouped conv3x3 + BN1 + ReLU via MFMA.
// Block: 16x16 px tile of one (b,g); 4 waves; wave = 4 rows x 32 co.
// LDS: x-tile [18*18 px][ci stride 40] bf16 = 25920 B (reused for epilogue).
__global__ __launch_bounds__(256) void conv1_mfma(
    const unsigned short* __restrict__ y0, const unsigned short* __restrict__ w1b,
    const float* __restrict__ g1, const float* __restrict__ b1,
    const float* __restrict__ m1, const float* __restrict__ v1,
    unsigned short* __restrict__ h1t) {
  __shared__ unsigned short xt[324 * 40];

  int blk  = blockIdx.x;              // 4096 = 8b * 8g * 64 tiles
  int tile = blk & 63;
  int g    = (blk >> 6) & 7;
  int b    = blk >> 9;
  int h0   = (tile >> 3) * 16;
  int w0   = (tile & 7) * 16;
  int tid  = threadIdx.x;

  // staging: batch all 6 global loads into regs first (one latency wait),
  // then ds_write. y0 is [px][ci32] -> 16B vec per task.
  const unsigned short* xsrc = y0 + (size_t)(b * 8 + g) * HW * 32;
  short8 sv[6];
#pragma unroll
  for (int t = 0; t < 6; ++t) {
    int j = tid + t * 256;
    short8 v = (short8){0, 0, 0, 0, 0, 0, 0, 0};
    if (j < 1296) {
      int r = j >> 2, part = j & 3;
      int yy = r / 18, xx = r - yy * 18;
      int gh = h0 - 1 + yy, gw = w0 - 1 + xx;
      if ((unsigned)gh < 128u && (unsigned)gw < 128u)
        v = *(const short8*)&xsrc[(size_t)(gh * 128 + gw) * 32 + part * 8];
    }
    sv[t] = v;
  }
#pragma unroll
  for (int t = 0; t < 6; ++t) {
    int j = tid + t * 256;
    if (j < 1296) {
      int r = j >> 2, part = j & 3;
      *(short8*)&xt[r * 40 + part * 8] = sv[t];
    }
  }

  int wv = tid >> 6, lane = tid & 63, q = lane >> 4, n = lane & 15;

  // B-frags from global (L2-resident, 18 KB/group): [g][khw][co][ci32]
  short8 bf[9][2];
  const unsigned short* wgb = w1b + (size_t)g * 9 * 32 * 32;
#pragma unroll
  for (int khw = 0; khw < 9; ++khw) {
#pragma unroll
    for (int half = 0; half < 2; ++half)
      bf[khw][half] =
          *(const short8*)&wgb[(khw * 32 + half * 16 + n) * 32 + q * 8];
  }

  __syncthreads();

  floatx4 acc[4][2];
#pragma unroll
  for (int r = 0; r < 4; ++r)
#pragma unroll
    for (int half = 0; half < 2; ++half) acc[r][half] = (floatx4){0.f, 0.f, 0.f, 0.f};

#pragma unroll
  for (int r = 0; r < 4; ++r) {
    int row = wv * 4 + r;
#pragma unroll
    for (int khw = 0; khw < 9; ++khw) {
      int kh = khw / 3, kw = khw % 3;
      short8 a = *(const short8*)&xt[((row + kh) * 18 + kw + n) * 40 + q * 8];
      acc[r][0] = mfma16(a, bf[khw][0], acc[r][0]);
      acc[r][1] = mfma16(a, bf[khw][1], acc[r][1]);
    }
  }

  float inv[2], bias[2];
#pragma unroll
  for (int half = 0; half < 2; ++half) {
    int cc = g * 32 + half * 16 + n;
    inv[half]  = g1[cc] * rsqrtf(v1[cc] + EPS);
    bias[half] = b1[cc] - m1[cc] * inv[half];
  }

  __syncthreads();                     // xt reads done; reuse as [px256][co40]

#pragma unroll
  for (int r = 0; r < 4; ++r) {
    int pr = (wv * 4 + r) * 16;
#pragma unroll
    for (int half = 0; half < 2; ++half) {
      int co = half * 16 + n;
#pragma unroll
      for (int reg = 0; reg < 4; ++reg) {
        int px = pr + q * 4 + reg;
        float v = fmaxf(acc[r][half][reg] * inv[half] + bias[half], 0.f);
        xt[px * 40 + co] = f2bf(v);
      }
    }
  }

  __syncthreads();

  // coalesced h1t store: thread = one px (16x16 tile), 4x16B
  unsigned short* hb = h1t + (size_t)(b * 8 + g) * HW * 32;
  int ph = tid >> 4, pw = tid & 15;
  size_t gp = (size_t)((h0 + ph) * 128 + (w0 + pw)) * 32;
#pragma unroll
  for (int k = 0; k < 4; ++k)
    *(short8*)&hb[gp + k * 8] = *(const short8*)&xt[tid * 40 + k * 8];
}

// 1x1 conv + BN2 + residual. Register GEMM: block = 64 px x 256 co of one b;
// wave = 64 px x 64 co. K = 256 (8 slabs of 32 = one group each).
// A-slabs (4KB contiguous) staged via global_load_lds, 3-buffer pipeline,
// depth-2 prefetch with counted vmcnt (T3-minimum). B frags from L2.
__global__ __launch_bounds__(256) void conv2_mfma(
    const unsigned short* __restrict__ h1t, const unsigned short* __restrict__ w2b,
    const float* __restrict__ g2, const float* __restrict__ b2,
    const float* __restrict__ m2, const float* __restrict__ v2,
    float* __restrict__ out) {
  __shared__ unsigned short As[3][2048];    // 3 x 4KB slabs

  int blk = blockIdx.x;               // 2048 = 8b * 256 px-tiles
  int b   = blk >> 8;
  int px0 = (blk & 255) * 64;
  int tid = threadIdx.x;
  int wv = tid >> 6, lane = tid & 63, q = lane >> 4, n = lane & 15;

  const unsigned short* sb = h1t + ((size_t)b * 8 * HW + px0) * 32;

  // wave wv stages its 1KB quarter: per-lane global src, wave-uniform LDS dst
#define STAGE(S, BUF)                                                         \
  __builtin_amdgcn_global_load_lds(                                           \
      (const __attribute__((address_space(1))) unsigned int*)(sb +            \
          (size_t)(S) * HW * 32 + wv * 512 + lane * 8),                       \
      (__attribute__((address_space(3))) unsigned int*)&As[BUF][wv * 512],    \
      16, 0, 0)

  floatx4 acc[4][4];                  // [mt][nt]
#pragma unroll
  for (int mt = 0; mt < 4; ++mt)
#pragma unroll
    for (int nt = 0; nt < 4; ++nt) acc[mt][nt] = (floatx4){0.f, 0.f, 0.f, 0.f};

  STAGE(0, 0);
  STAGE(1, 1);
  asm volatile("s_waitcnt vmcnt(1)");  // slab 0 resident (1 stage may remain)
  __syncthreads();

#pragma unroll
  for (int s = 0; s < 8; ++s) {       // K-slab = group s
    if (s < 6) STAGE(s + 2, (s + 2) % 3);
    short8 bb[4];
#pragma unroll
    for (int nt = 0; nt < 4; ++nt)
      bb[nt] =
          *(const short8*)&w2b[(wv * 64 + nt * 16 + n) * 256 + s * 32 + q * 8];
    const unsigned short* Ab = &As[s % 3][0];
#pragma unroll
    for (int mt = 0; mt < 4; ++mt) {
      short8 a = *(const short8*)&Ab[(mt * 16 + n) * 32 + q * 8];
#pragma unroll
      for (int nt = 0; nt < 4; ++nt) acc[mt][nt] = mfma16(a, bb[nt], acc[mt][nt]);
    }
    if (s < 6) asm volatile("s_waitcnt vmcnt(1)");       // slab s+1 resident
    else if (s == 6) asm volatile("s_waitcnt vmcnt(0)"); // slab 7 resident
    if (s < 7) __syncthreads();
  }
#undef STAGE

#pragma unroll
  for (int nt = 0; nt < 4; ++nt) {
    int co = wv * 64 + nt * 16 + n;
    float inv  = g2[co] * rsqrtf(v2[co] + EPS);
    float bias = b2[co] - m2[co] * inv;
    float* ob = out + (size_t)(b * 256 + co) * HW;
#pragma unroll
    for (int mt = 0; mt < 4; ++mt) {
      int px = px0 + mt * 16 + q * 4;
      float4 sv = *(float4*)&ob[px];
      sv.x += acc[mt][nt][0] * inv + bias;
      sv.y += acc[mt][nt][1] * inv + bias;
      sv.z += acc[mt][nt][2] * inv + bias;
      sv.w += acc[mt][nt][3] * inv + bias;
      *(float4*)&ob[px] = sv;
    }
  }
}

extern "C" void kernel_launch(void* const* d_in, const int* in_sizes, int n_in,
                              void* d_out, int out_size, void* d_ws,
                              size_t ws_size, hipStream_t stream) {
  const float* x   = (const float*)d_in[0];
  const float* dw  = (const float*)d_in[1];
  const float* roi = (const float*)d_in[2];
  const float* w1  = (const float*)d_in[3];
  const float* g1  = (const float*)d_in[4];
  const float* b1  = (const float*)d_in[5];
  const float* m1  = (const float*)d_in[6];
  const float* v1  = (const float*)d_in[7];
  const float* w2  = (const float*)d_in[8];
  const float* g2  = (const float*)d_in[9];
  const float* b2  = (const float*)d_in[10];
  const float* m2  = (const float*)d_in[11];
  const float* v2  = (const float*)d_in[12];
  float* out = (float*)d_out;

  char* ws = (char*)d_ws;
  unsigned short* y0b = (unsigned short*)ws;                 // 67108864 B
  unsigned short* h1t = (unsigned short*)(ws + 67108864);    // 67108864 B
  unsigned short* w1b = (unsigned short*)(ws + 134217728);   // 147456 B
  unsigned short* w2b = (unsigned short*)(ws + 134365184);   // 131072 B

  ska_kernel<<<33312, 256, 0, stream>>>(x, dw, roi, out, y0b, w1, w2, w1b, w2b);
  conv1_mfma<<<4096, 256, 0, stream>>>(y0b, w1b, g1, b1, m1, v1, h1t);
  conv2_mfma<<<2048, 256, 0, stream>>>(h1t, w2b, g2, b2, m2, v2, out);
}